// Round 3
// baseline (1227.791 us; speedup 1.0000x reference)
//
#include <hip/hip_runtime.h>
#include <stdint.h>

#define M_TOK 8192   // B*T
#define DDIM  2048
#define HDIM  4096
#define NEXP  16
#define ODIM  2048

typedef __attribute__((ext_vector_type(8))) __bf16 bf16x8;
typedef __attribute__((ext_vector_type(4))) float  f32x4;

__device__ __forceinline__ unsigned short f2bf(float f) {
    unsigned int u = __float_as_uint(f);
    unsigned int r = (u + 0x7FFFu + ((u >> 16) & 1u)) >> 16;   // RNE
    return (unsigned short)r;
}
__device__ __forceinline__ float bf2f(unsigned short s) {
    return __uint_as_float(((unsigned int)s) << 16);
}

// DPP move (returns the lane-permuted copy; full row/bank masks, bound_ctrl on).
// Only direction-unambiguous controls are used: quad_perm (explicit map) and
// row_ror:8 (== xor8 under either rotation convention).
template <int CTRL>
__device__ __forceinline__ float dpp_mov(float x) {
    return __int_as_float(
        __builtin_amdgcn_update_dpp(0, __float_as_int(x), CTRL, 0xF, 0xF, true));
}
// xor4 lane exchange via ds_swizzle BitMode (symmetric, no direction convention):
// offset = (xor_mask<<10)|(or<<5)|and = (4<<10)|0x1F
__device__ __forceinline__ float swz_xor4(float x) {
    return __int_as_float(__builtin_amdgcn_ds_swizzle(__float_as_int(x), 0x101F));
}

// ---------------- preprocessing ----------------

__global__ void split_x_kernel(const float* __restrict__ x,
                               ushort* __restrict__ xh, ushort* __restrict__ xl) {
    size_t i = ((size_t)blockIdx.x * 256 + threadIdx.x) * 4;
    float4 v = *(const float4*)(x + i);
    float f[4] = {v.x, v.y, v.z, v.w};
    ushort hu[4], lu[4];
#pragma unroll
    for (int u = 0; u < 4; ++u) {
        hu[u] = f2bf(f[u]);
        lu[u] = f2bf(f[u] - bf2f(hu[u]));
    }
    *(ushort4*)(xh + i) = make_ushort4(hu[0], hu[1], hu[2], hu[3]);
    *(ushort4*)(xl + i) = make_ushort4(lu[0], lu[1], lu[2], lu[3]);
}

__global__ void transpose_split_w1_kernel(const float* __restrict__ W1,
                                          ushort* __restrict__ th, ushort* __restrict__ tl) {
    __shared__ float tile[64][65];
    int h0 = (blockIdx.x & 63) * 64;
    int d0 = (blockIdx.x >> 6) * 64;
    int r = threadIdx.x >> 4;
    int c = (threadIdx.x & 15) * 4;
#pragma unroll
    for (int rr = 0; rr < 4; ++rr) {
        int row = rr * 16 + r;
        float4 v = *(const float4*)(W1 + (size_t)(d0 + row) * HDIM + h0 + c);
        tile[row][c + 0] = v.x; tile[row][c + 1] = v.y;
        tile[row][c + 2] = v.z; tile[row][c + 3] = v.w;
    }
    __syncthreads();
#pragma unroll
    for (int rr = 0; rr < 4; ++rr) {
        int hrow = rr * 16 + r;
        ushort hu[4], lu[4];
#pragma unroll
        for (int u = 0; u < 4; ++u) {
            float f = tile[c + u][hrow];
            hu[u] = f2bf(f);
            lu[u] = f2bf(f - bf2f(hu[u]));
        }
        size_t o = (size_t)(h0 + hrow) * DDIM + d0 + c;
        *(ushort4*)(th + o) = make_ushort4(hu[0], hu[1], hu[2], hu[3]);
        *(ushort4*)(tl + o) = make_ushort4(lu[0], lu[1], lu[2], lu[3]);
    }
}

__global__ void transpose_we_kernel(const float* __restrict__ We, ushort* __restrict__ wt) {
    __shared__ float tile[64][65];
    int e = blockIdx.y;
    int o0 = (blockIdx.x & 31) * 64;
    int d0 = (blockIdx.x >> 5) * 64;
    const float* src = We + (size_t)e * DDIM * ODIM;
    ushort* dst = wt + (size_t)e * ODIM * DDIM;
    int r = threadIdx.x >> 4;
    int c = (threadIdx.x & 15) * 4;
#pragma unroll
    for (int rr = 0; rr < 4; ++rr) {
        int row = rr * 16 + r;
        float4 v = *(const float4*)(src + (size_t)(d0 + row) * ODIM + o0 + c);
        tile[row][c + 0] = v.x; tile[row][c + 1] = v.y;
        tile[row][c + 2] = v.z; tile[row][c + 3] = v.w;
    }
    __syncthreads();
#pragma unroll
    for (int rr = 0; rr < 4; ++rr) {
        int orow = rr * 16 + r;
        ushort hu[4];
#pragma unroll
        for (int u = 0; u < 4; ++u) hu[u] = f2bf(tile[c + u][orow]);
        *(ushort4*)(dst + (size_t)(o0 + orow) * DDIM + d0 + c) =
            make_ushort4(hu[0], hu[1], hu[2], hu[3]);
    }
}

// ---------------- GEMM core helpers (xor-swizzled LDS, 16B global_load_lds) ----------

__device__ __forceinline__ void stage_tile(const ushort* __restrict__ g0, int ld,
                                           ushort* lds0, int wave, int lane) {
#pragma unroll
    for (int j = 0; j < 4; ++j) {
        int L = wave * 256 + j * 64 + lane;
        int m = L >> 3;
        int kc = (L & 7) ^ (m & 7);
        const ushort* gp = g0 + (size_t)m * ld + kc * 8;
        ushort* lp = lds0 + (size_t)(wave * 256 + j * 64) * 8;
        __builtin_amdgcn_global_load_lds(
            (const __attribute__((address_space(1))) void*)gp,
            (__attribute__((address_space(3))) void*)lp, 16, 0, 0);
    }
}

__device__ __forceinline__ bf16x8 ldfrag(const ushort* lds0, int row, int kc) {
    return *(const bf16x8*)(lds0 + ((row << 3) + (kc ^ (row & 7))) * 8);
}

__device__ __forceinline__ void mfma_step(const ushort* As, const ushort* Bs,
                                          int wm, int wn, int mrow, int q,
                                          f32x4 (&acc)[4][4]) {
#pragma unroll
    for (int s = 0; s < 2; ++s) {
        bf16x8 af[4], bfr[4];
#pragma unroll
        for (int i = 0; i < 4; ++i) af[i] = ldfrag(As, wm + i * 16 + mrow, s * 4 + q);
#pragma unroll
        for (int j = 0; j < 4; ++j) bfr[j] = ldfrag(Bs, wn + j * 16 + mrow, s * 4 + q);
#pragma unroll
        for (int i = 0; i < 4; ++i)
#pragma unroll
            for (int j = 0; j < 4; ++j)
                acc[i][j] = __builtin_amdgcn_mfma_f32_16x16x32_bf16(
                    af[i], bfr[j], acc[i][j], 0, 0, 0);
    }
}

// Router GEMM1 + fused GEMM2:
//   h = relu([x_hi|x_lo|x_hi] @ [W1hi|W1hi|W1lo]^T + b1), K=3*2048 (never stored)
//   logits[tile_m rows] += h_tile @ W2[tile_n slice]  (partial, global atomics)
// Main loop: double-buffered LDS, ONE barrier per K-step, stage overlaps MFMA.
__global__ __launch_bounds__(256, 2) void gemm1_kernel(
    const ushort* __restrict__ xh, const ushort* __restrict__ xl,
    const ushort* __restrict__ wh, const ushort* __restrict__ wl,
    const float* __restrict__ b1, const float* __restrict__ W2,
    float* __restrict__ logits) {
    __shared__ ushort As0[8192];
    __shared__ ushort Bs0[8192];
    __shared__ ushort As1[8192];
    __shared__ ushort Bs1[8192];
    const int tile_m = (blockIdx.x & 63) << 7;
    const int tile_n = (blockIdx.x >> 6) << 7;
    const int tid = threadIdx.x;
    const int wave = tid >> 6, lane = tid & 63;
    const int q = lane >> 4, mrow = lane & 15;
    const int wm = (wave >> 1) << 6, wn = (wave & 1) << 6;
    f32x4 acc[4][4];
#pragma unroll
    for (int i = 0; i < 4; ++i)
#pragma unroll
        for (int j = 0; j < 4; ++j) acc[i][j] = {0.f, 0.f, 0.f, 0.f};

#define SRC_A(t) ((((t) >> 5) == 1 ? xl : xh) + (size_t)tile_m * DDIM + (((t) & 31) << 6))
#define SRC_B(t) ((((t) >> 5) == 2 ? wl : wh) + (size_t)tile_n * DDIM + (((t) & 31) << 6))

    // prologue: stage t=0 into buffer 0
    stage_tile(SRC_A(0), DDIM, As0, wave, lane);
    stage_tile(SRC_B(0), DDIM, Bs0, wave, lane);
    __syncthreads();

    for (int it = 0; it < 96; it += 2) {
        // stage t=it+1 into buffer 1, compute buffer 0
        stage_tile(SRC_A(it + 1), DDIM, As1, wave, lane);
        stage_tile(SRC_B(it + 1), DDIM, Bs1, wave, lane);
        mfma_step(As0, Bs0, wm, wn, mrow, q, acc);
        __syncthreads();
        // stage t=it+2 into buffer 0 (if any), compute buffer 1
        if (it + 2 < 96) {
            stage_tile(SRC_A(it + 2), DDIM, As0, wave, lane);
            stage_tile(SRC_B(it + 2), DDIM, Bs0, wave, lane);
        }
        mfma_step(As1, Bs1, wm, wn, mrow, q, acc);
        __syncthreads();
    }
#undef SRC_A
#undef SRC_B

    // ---- fused epilogue: partial logits from this 128x128 h-tile ----
    float b1v[4];
    f32x4 w2r[4][4];
#pragma unroll
    for (int j = 0; j < 4; ++j) {
        const int cc = tile_n + wn + j * 16 + mrow;
        b1v[j] = b1[cc];
        const float4* wp = (const float4*)(W2 + (size_t)cc * NEXP);
#pragma unroll
        for (int qq = 0; qq < 4; ++qq) {
            float4 v = wp[qq];
            w2r[j][qq] = (f32x4){v.x, v.y, v.z, v.w};
        }
    }
    float* part = (float*)As0;       // [2][128][16] floats = 16 KiB, reuses As0
    const int w01 = wave & 1;
    const bool pb0 = (mrow & 1) != 0, pb1 = (mrow & 2) != 0;
    const bool pb2 = (mrow & 4) != 0, pb3 = (mrow & 8) != 0;
    // after the tree, this lane holds the sum for expert E:
    const int E = (mrow & 3) | ((mrow & 8) >> 1) | ((mrow & 4) << 1);
#pragma unroll
    for (int i = 0; i < 4; ++i) {
#pragma unroll
        for (int r = 0; r < 4; ++r) {
            const int rl = wm + i * 16 + q * 4 + r;
            float ll[16];
#pragma unroll
            for (int e = 0; e < 16; ++e) ll[e] = 0.f;
#pragma unroll
            for (int j = 0; j < 4; ++j) {
                float v = acc[i][j][r] + b1v[j];
                v = v > 0.f ? v : 0.f;
#pragma unroll
                for (int e = 0; e < 16; ++e)
                    ll[e] = fmaf(v, w2r[j][e >> 2][e & 3], ll[e]);
            }
            // halving tree across the 16 mrow lanes: 16 -> 8 -> 4 -> 2 -> 1
            float s1[8];
#pragma unroll
            for (int e2 = 0; e2 < 8; ++e2) {
                float a = ll[2 * e2], b = ll[2 * e2 + 1];
                float y = pb0 ? b : a, z = pb0 ? a : b;
                s1[e2] = y + dpp_mov<0xB1>(z);          // quad_perm xor1
            }
            float s2[4];
#pragma unroll
            for (int e2 = 0; e2 < 4; ++e2) {
                float a = s1[2 * e2], b = s1[2 * e2 + 1];
                float y = pb1 ? b : a, z = pb1 ? a : b;
                s2[e2] = y + dpp_mov<0x4E>(z);          // quad_perm xor2
            }
            float s3[2];
#pragma unroll
            for (int e2 = 0; e2 < 2; ++e2) {
                float a = s2[2 * e2], b = s2[2 * e2 + 1];
                float y = pb3 ? b : a, z = pb3 ? a : b;
                s3[e2] = y + dpp_mov<0x128>(z);         // row_ror:8 == xor8
            }
            {
                float a = s3[0], b = s3[1];
                float y = pb2 ? b : a, z = pb2 ? a : b;
                float fin = y + swz_xor4(z);            // ds_swizzle xor4 (symmetric)
                part[(size_t)(w01 * 128 + rl) * 16 + E] = fin;
            }
        }
    }
    __syncthreads();
    for (int idx = tid; idx < 2048; idx += 256) {
        float s = part[idx] + part[2048 + idx];
        atomicAdd(&logits[(size_t)(tile_m + (idx >> 4)) * NEXP + (idx & 15)], s);
    }
}

// softmax -> mask -> gates, k_per_token, and per-expert compacted token lists
__global__ void gates_kernel(const float* __restrict__ logits,
                             const float* __restrict__ b2,
                             float* __restrict__ gates, float* __restrict__ kout,
                             int* __restrict__ cnt, int* __restrict__ list) {
    const int t = blockIdx.x * 256 + threadIdx.x;
    float l[16];
    const float4* lp = (const float4*)(logits + (size_t)t * 16);
#pragma unroll
    for (int i = 0; i < 4; ++i) {
        float4 v = lp[i];
        l[i * 4] = v.x; l[i * 4 + 1] = v.y; l[i * 4 + 2] = v.z; l[i * 4 + 3] = v.w;
    }
#pragma unroll
    for (int i = 0; i < 16; ++i) l[i] += b2[i];
    float lmax = l[0];
#pragma unroll
    for (int i = 1; i < 16; ++i) lmax = fmaxf(lmax, l[i]);
    float p[16], S = 0.f;
#pragma unroll
    for (int i = 0; i < 16; ++i) { p[i] = expf(l[i] - lmax); S += p[i]; }
#pragma unroll
    for (int i = 0; i < 16; ++i) p[i] /= S;
    float pmax = p[0];
#pragma unroll
    for (int i = 1; i < 16; ++i) pmax = fmaxf(pmax, p[i]);
    const float thr = 0.5f * pmax;
    int k = 0;
    float g[16];
#pragma unroll
    for (int i = 0; i < 16; ++i) {
        bool m = p[i] >= thr;
        g[i] = m ? p[i] : 0.f;
        k += m ? 1 : 0;
        if (m) {
            int pos = atomicAdd(&cnt[i], 1);
            list[i * M_TOK + pos] = t;
        }
    }
    float4* gp = (float4*)(gates + (size_t)t * 16);
#pragma unroll
    for (int i = 0; i < 4; ++i)
        gp[i] = make_float4(g[i * 4], g[i * 4 + 1], g[i * 4 + 2], g[i * 4 + 3]);
    kout[t] = (float)k;
}

// out[t,:] = sum_e g[t,e] * be[e,:]  (base for the sparse atomic accumulate)
__global__ void init_out_kernel(const float* __restrict__ gates,
                                const float* __restrict__ be, float* __restrict__ out) {
    const int t = blockIdx.x;
    const int tid = threadIdx.x;
    __shared__ float g[16];
    if (tid < 16) g[tid] = gates[(size_t)t * 16 + tid];
    __syncthreads();
    const int c0 = tid * 8;
    float a[8] = {0.f, 0.f, 0.f, 0.f, 0.f, 0.f, 0.f, 0.f};
#pragma unroll
    for (int e = 0; e < 16; ++e) {
        float ge = g[e];
        if (ge != 0.f) {
            float4 v1 = *(const float4*)(be + (size_t)e * ODIM + c0);
            float4 v2 = *(const float4*)(be + (size_t)e * ODIM + c0 + 4);
            a[0] = fmaf(ge, v1.x, a[0]); a[1] = fmaf(ge, v1.y, a[1]);
            a[2] = fmaf(ge, v1.z, a[2]); a[3] = fmaf(ge, v1.w, a[3]);
            a[4] = fmaf(ge, v2.x, a[4]); a[5] = fmaf(ge, v2.y, a[5]);
            a[6] = fmaf(ge, v2.z, a[6]); a[7] = fmaf(ge, v2.w, a[7]);
        }
    }
    *(float4*)(out + (size_t)t * ODIM + c0)     = make_float4(a[0], a[1], a[2], a[3]);
    *(float4*)(out + (size_t)t * ODIM + c0 + 4) = make_float4(a[4], a[5], a[6], a[7]);
}

// Sparse expert GEMM: for expert e, gathered 128-token chunk, 128-col n-tile:
// out[tok,:] += g[tok,e] * (x[tok,:] @ We[e]).  K = 2048 (32 iters).
__global__ __launch_bounds__(256, 3) void moe_sparse_kernel(
    const ushort* __restrict__ xh, const ushort* __restrict__ weT,
    const float* __restrict__ gates, const int* __restrict__ cnt,
    const int* __restrict__ list, float* __restrict__ out) {
    const int bx = blockIdx.x;
    const int e = bx >> 10;
    const int chunk = (bx >> 4) & 63;
    const int ntile = bx & 15;
    const int ce = cnt[e];
    const int row0 = chunk << 7;
    if (row0 >= ce) return;
    const int rows = min(128, ce - row0);

    __shared__ ushort As[8192];
    __shared__ ushort Bs[8192];
    __shared__ int toks[128];
    __shared__ float gv[128];

    const int tid = threadIdx.x;
    if (tid < 128) {
        int t = list[e * M_TOK + row0 + min(tid, rows - 1)];
        toks[tid] = t;
        gv[tid] = gates[(size_t)t * NEXP + e];
    }
    __syncthreads();

    const int wave = tid >> 6, lane = tid & 63;
    const int q = lane >> 4, mrow = lane & 15;
    const int wm = (wave >> 1) << 6, wn = (wave & 1) << 6;

    // per-lane fixed staging pointers (A rows gathered; constant over K loop)
    const ushort* agp[4];
    const ushort* bgp[4];
    ushort* alp[4];
    ushort* blp[4];
    const ushort* wbase = weT + ((size_t)e * ODIM + (ntile << 7)) * DDIM;
#pragma unroll
    for (int j = 0; j < 4; ++j) {
        int L = wave * 256 + j * 64 + lane;
        int m = L >> 3;
        int kc = (L & 7) ^ (m & 7);
        agp[j] = xh + (size_t)toks[m] * DDIM + kc * 8;
        bgp[j] = wbase + (size_t)m * DDIM + kc * 8;
        alp[j] = As + (size_t)L * 8;
        blp[j] = Bs + (size_t)L * 8;
    }

    f32x4 acc[4][4];
#pragma unroll
    for (int i = 0; i < 4; ++i)
#pragma unroll
        for (int j = 0; j < 4; ++j) acc[i][j] = {0.f, 0.f, 0.f, 0.f};

    for (int it = 0; it < 32; ++it) {
        const int k0 = it << 6;
        __syncthreads();
#pragma unroll
        for (int j = 0; j < 4; ++j) {
            __builtin_amdgcn_global_load_lds(
                (const __attribute__((address_space(1))) void*)(agp[j] + k0),
                (__attribute__((address_space(3))) void*)alp[j], 16, 0, 0);
            __builtin_amdgcn_global_load_lds(
                (const __attribute__((address_space(1))) void*)(bgp[j] + k0),
                (__attribute__((address_space(3))) void*)blp[j], 16, 0, 0);
        }
        __syncthreads();
        mfma_step(As, Bs, wm, wn, mrow, q, acc);
    }

    // epilogue: atomic accumulate g * acc into out rows
#pragma unroll
    for (int i = 0; i < 4; ++i) {
        const int rl = wm + i * 16 + q * 4;
#pragma unroll
        for (int r = 0; r < 4; ++r) {
            const int lrow = rl + r;
            if (lrow < rows) {
                const int t = toks[lrow];
                const float g = gv[lrow];
                float* orow = out + (size_t)t * ODIM + (ntile << 7) + wn + mrow;
#pragma unroll
                for (int j = 0; j < 4; ++j)
                    atomicAdd(orow + j * 16, g * acc[i][j][r]);
            }
        }
    }
}

extern "C" void kernel_launch(void* const* d_in, const int* in_sizes, int n_in,
                              void* d_out, int out_size, void* d_ws, size_t ws_size,
                              hipStream_t stream) {
    const float* x  = (const float*)d_in[0];
    const float* W1 = (const float*)d_in[1];
    const float* b1 = (const float*)d_in[2];
    const float* W2 = (const float*)d_in[3];
    const float* b2 = (const float*)d_in[4];
    const float* We = (const float*)d_in[5];
    const float* be = (const float*)d_in[6];
    float* out  = (float*)d_out;
    float* kout = out + (size_t)M_TOK * ODIM;

    char* ws = (char*)d_ws;
    ushort* x_hi   = (ushort*)(ws);                 //  33,554,432 B
    ushort* x_lo   = (ushort*)(ws + 33554432);      //  33,554,432 B
    ushort* w1t_hi = (ushort*)(ws + 67108864);      //  16,777,216 B
    // w1t_lo region is dead after gemm1; cnt/list reuse it:
    ushort* w1t_lo = (ushort*)(ws + 83886080);      //  16,777,216 B
    int*    cnt    = (int*)   (ws + 83886080);      //  64 B (after gemm1)
    int*    list   = (int*)   (ws + 83887104);      //  512 KiB (after gemm1)
    ushort* weT    = (ushort*)(ws + 100663296);     // 134,217,728 B
    float*  logits = (float*) (ws + 234881024);     //  512 KiB
    float*  gates  = (float*) (ws + 235405312);     //  512 KiB

    hipMemsetAsync(logits, 0, (size_t)M_TOK * NEXP * sizeof(float), stream);
    split_x_kernel<<<16384, 256, 0, stream>>>(x, x_hi, x_lo);
    transpose_split_w1_kernel<<<2048, 256, 0, stream>>>(W1, w1t_hi, w1t_lo);
    gemm1_kernel<<<2048, 256, 0, stream>>>(x_hi, x_lo, w1t_hi, w1t_lo, b1, W2, logits);
    hipMemsetAsync(cnt, 0, 64, stream);
    gates_kernel<<<32, 256, 0, stream>>>(logits, b2, gates, kout, cnt, list);
    dim3 gwe(1024, 16);
    transpose_we_kernel<<<gwe, 256, 0, stream>>>(We, weT);
    init_out_kernel<<<M_TOK, 256, 0, stream>>>(gates, be, out);
    moe_sparse_kernel<<<16384, 256, 0, stream>>>(x_hi, weT, gates, cnt, list, out);
}

// Round 4
// 1224.790 us; speedup vs baseline: 1.0025x; 1.0025x over previous
//
#include <hip/hip_runtime.h>
#include <stdint.h>

#define M_TOK 8192   // B*T
#define DDIM  2048
#define HDIM  4096
#define NEXP  16
#define ODIM  2048

typedef __attribute__((ext_vector_type(8))) __bf16 bf16x8;
typedef __attribute__((ext_vector_type(4))) float  f32x4;

__device__ __forceinline__ unsigned short f2bf(float f) {
    unsigned int u = __float_as_uint(f);
    unsigned int r = (u + 0x7FFFu + ((u >> 16) & 1u)) >> 16;   // RNE
    return (unsigned short)r;
}
__device__ __forceinline__ float bf2f(unsigned short s) {
    return __uint_as_float(((unsigned int)s) << 16);
}

// DPP move (returns the lane-permuted copy; full row/bank masks, bound_ctrl on).
// Only direction-unambiguous controls are used: quad_perm (explicit map) and
// row_ror:8 (== xor8 under either rotation convention).
template <int CTRL>
__device__ __forceinline__ float dpp_mov(float x) {
    return __int_as_float(
        __builtin_amdgcn_update_dpp(0, __float_as_int(x), CTRL, 0xF, 0xF, true));
}
// xor4 lane exchange via ds_swizzle BitMode (symmetric, no direction convention):
// offset = (xor_mask<<10)|(or<<5)|and = (4<<10)|0x1F
__device__ __forceinline__ float swz_xor4(float x) {
    return __int_as_float(__builtin_amdgcn_ds_swizzle(__float_as_int(x), 0x101F));
}

// ---------------- preprocessing ----------------

__global__ void split_x_kernel(const float* __restrict__ x,
                               ushort* __restrict__ xh, ushort* __restrict__ xl) {
    size_t i = ((size_t)blockIdx.x * 256 + threadIdx.x) * 4;
    float4 v = *(const float4*)(x + i);
    float f[4] = {v.x, v.y, v.z, v.w};
    ushort hu[4], lu[4];
#pragma unroll
    for (int u = 0; u < 4; ++u) {
        hu[u] = f2bf(f[u]);
        lu[u] = f2bf(f[u] - bf2f(hu[u]));
    }
    *(ushort4*)(xh + i) = make_ushort4(hu[0], hu[1], hu[2], hu[3]);
    *(ushort4*)(xl + i) = make_ushort4(lu[0], lu[1], lu[2], lu[3]);
}

__global__ void transpose_split_w1_kernel(const float* __restrict__ W1,
                                          ushort* __restrict__ th, ushort* __restrict__ tl) {
    __shared__ float tile[64][65];
    int h0 = (blockIdx.x & 63) * 64;
    int d0 = (blockIdx.x >> 6) * 64;
    int r = threadIdx.x >> 4;
    int c = (threadIdx.x & 15) * 4;
#pragma unroll
    for (int rr = 0; rr < 4; ++rr) {
        int row = rr * 16 + r;
        float4 v = *(const float4*)(W1 + (size_t)(d0 + row) * HDIM + h0 + c);
        tile[row][c + 0] = v.x; tile[row][c + 1] = v.y;
        tile[row][c + 2] = v.z; tile[row][c + 3] = v.w;
    }
    __syncthreads();
#pragma unroll
    for (int rr = 0; rr < 4; ++rr) {
        int hrow = rr * 16 + r;
        ushort hu[4], lu[4];
#pragma unroll
        for (int u = 0; u < 4; ++u) {
            float f = tile[c + u][hrow];
            hu[u] = f2bf(f);
            lu[u] = f2bf(f - bf2f(hu[u]));
        }
        size_t o = (size_t)(h0 + hrow) * DDIM + d0 + c;
        *(ushort4*)(th + o) = make_ushort4(hu[0], hu[1], hu[2], hu[3]);
        *(ushort4*)(tl + o) = make_ushort4(lu[0], lu[1], lu[2], lu[3]);
    }
}

__global__ void transpose_we_kernel(const float* __restrict__ We, ushort* __restrict__ wt) {
    __shared__ float tile[64][65];
    int e = blockIdx.y;
    int o0 = (blockIdx.x & 31) * 64;
    int d0 = (blockIdx.x >> 5) * 64;
    const float* src = We + (size_t)e * DDIM * ODIM;
    ushort* dst = wt + (size_t)e * ODIM * DDIM;
    int r = threadIdx.x >> 4;
    int c = (threadIdx.x & 15) * 4;
#pragma unroll
    for (int rr = 0; rr < 4; ++rr) {
        int row = rr * 16 + r;
        float4 v = *(const float4*)(src + (size_t)(d0 + row) * ODIM + o0 + c);
        tile[row][c + 0] = v.x; tile[row][c + 1] = v.y;
        tile[row][c + 2] = v.z; tile[row][c + 3] = v.w;
    }
    __syncthreads();
#pragma unroll
    for (int rr = 0; rr < 4; ++rr) {
        int orow = rr * 16 + r;
        ushort hu[4];
#pragma unroll
        for (int u = 0; u < 4; ++u) hu[u] = f2bf(tile[c + u][orow]);
        *(ushort4*)(dst + (size_t)(o0 + orow) * DDIM + d0 + c) =
            make_ushort4(hu[0], hu[1], hu[2], hu[3]);
    }
}

// ---------------- GEMM core helpers (xor-swizzled LDS, 16B global_load_lds) ----------

__device__ __forceinline__ void stage_tile(const ushort* __restrict__ g0, int ld,
                                           ushort* lds0, int wave, int lane) {
#pragma unroll
    for (int j = 0; j < 4; ++j) {
        int L = wave * 256 + j * 64 + lane;
        int m = L >> 3;
        int kc = (L & 7) ^ (m & 7);
        const ushort* gp = g0 + (size_t)m * ld + kc * 8;
        ushort* lp = lds0 + (size_t)(wave * 256 + j * 64) * 8;
        __builtin_amdgcn_global_load_lds(
            (const __attribute__((address_space(1))) void*)gp,
            (__attribute__((address_space(3))) void*)lp, 16, 0, 0);
    }
}

__device__ __forceinline__ bf16x8 ldfrag(const ushort* lds0, int row, int kc) {
    return *(const bf16x8*)(lds0 + ((row << 3) + (kc ^ (row & 7))) * 8);
}

__device__ __forceinline__ void mfma_step(const ushort* As, const ushort* Bs,
                                          int wm, int wn, int mrow, int q,
                                          f32x4 (&acc)[4][4]) {
#pragma unroll
    for (int s = 0; s < 2; ++s) {
        bf16x8 af[4], bfr[4];
#pragma unroll
        for (int i = 0; i < 4; ++i) af[i] = ldfrag(As, wm + i * 16 + mrow, s * 4 + q);
#pragma unroll
        for (int j = 0; j < 4; ++j) bfr[j] = ldfrag(Bs, wn + j * 16 + mrow, s * 4 + q);
#pragma unroll
        for (int i = 0; i < 4; ++i)
#pragma unroll
            for (int j = 0; j < 4; ++j)
                acc[i][j] = __builtin_amdgcn_mfma_f32_16x16x32_bf16(
                    af[i], bfr[j], acc[i][j], 0, 0, 0);
    }
}

// Router GEMM1 + fused GEMM2:
//   h = relu([x_hi|x_lo|x_hi] @ [W1hi|W1hi|W1lo]^T + b1), K=3*2048 (never stored)
//   logits[tile_m rows] += h_tile @ W2[tile_n slice]  (partial, global atomics)
// Main loop: SINGLE-buffer LDS (32 KB). Dbuf was tried (r3): 64 KB LDS halves
// the block cap -> occupancy 30->22%, MfmaUtil 43%, +33 us. Reverted.
__global__ __launch_bounds__(256, 3) void gemm1_kernel(
    const ushort* __restrict__ xh, const ushort* __restrict__ xl,
    const ushort* __restrict__ wh, const ushort* __restrict__ wl,
    const float* __restrict__ b1, const float* __restrict__ W2,
    float* __restrict__ logits) {
    __shared__ ushort As[8192];
    __shared__ ushort Bs[8192];
    const int tile_m = (blockIdx.x & 63) << 7;
    const int tile_n = (blockIdx.x >> 6) << 7;
    const int tid = threadIdx.x;
    const int wave = tid >> 6, lane = tid & 63;
    const int q = lane >> 4, mrow = lane & 15;
    const int wm = (wave >> 1) << 6, wn = (wave & 1) << 6;
    f32x4 acc[4][4];
#pragma unroll
    for (int i = 0; i < 4; ++i)
#pragma unroll
        for (int j = 0; j < 4; ++j) acc[i][j] = {0.f, 0.f, 0.f, 0.f};

    for (int it = 0; it < 96; ++it) {
        const int phase = it >> 5;
        const ushort* Ab = (phase == 1) ? xl : xh;
        const ushort* Bb = (phase == 2) ? wl : wh;
        const int k0 = (it & 31) << 6;
        __syncthreads();
        stage_tile(Ab + (size_t)tile_m * DDIM + k0, DDIM, As, wave, lane);
        stage_tile(Bb + (size_t)tile_n * DDIM + k0, DDIM, Bs, wave, lane);
        __syncthreads();
        mfma_step(As, Bs, wm, wn, mrow, q, acc);
    }

    // ---- fused epilogue: partial logits from this 128x128 h-tile ----
    float b1v[4];
    f32x4 w2r[4][4];
#pragma unroll
    for (int j = 0; j < 4; ++j) {
        const int cc = tile_n + wn + j * 16 + mrow;
        b1v[j] = b1[cc];
        const float4* wp = (const float4*)(W2 + (size_t)cc * NEXP);
#pragma unroll
        for (int qq = 0; qq < 4; ++qq) {
            float4 v = wp[qq];
            w2r[j][qq] = (f32x4){v.x, v.y, v.z, v.w};
        }
    }
    __syncthreads();                 // all waves done reading As/Bs
    float* part = (float*)As;        // [2][128][16] floats = 16 KiB, reuses As
    const int w01 = wave & 1;
    const bool pb0 = (mrow & 1) != 0, pb1 = (mrow & 2) != 0;
    const bool pb2 = (mrow & 4) != 0, pb3 = (mrow & 8) != 0;
    // after the tree, this lane holds the sum for expert E:
    const int E = (mrow & 3) | ((mrow & 8) >> 1) | ((mrow & 4) << 1);
#pragma unroll
    for (int i = 0; i < 4; ++i) {
#pragma unroll
        for (int r = 0; r < 4; ++r) {
            const int rl = wm + i * 16 + q * 4 + r;
            float ll[16];
#pragma unroll
            for (int e = 0; e < 16; ++e) ll[e] = 0.f;
#pragma unroll
            for (int j = 0; j < 4; ++j) {
                float v = acc[i][j][r] + b1v[j];
                v = v > 0.f ? v : 0.f;
#pragma unroll
                for (int e = 0; e < 16; ++e)
                    ll[e] = fmaf(v, w2r[j][e >> 2][e & 3], ll[e]);
            }
            // halving tree across the 16 mrow lanes: 16 -> 8 -> 4 -> 2 -> 1
            float s1[8];
#pragma unroll
            for (int e2 = 0; e2 < 8; ++e2) {
                float a = ll[2 * e2], b = ll[2 * e2 + 1];
                float y = pb0 ? b : a, z = pb0 ? a : b;
                s1[e2] = y + dpp_mov<0xB1>(z);          // quad_perm xor1
            }
            float s2[4];
#pragma unroll
            for (int e2 = 0; e2 < 4; ++e2) {
                float a = s1[2 * e2], b = s1[2 * e2 + 1];
                float y = pb1 ? b : a, z = pb1 ? a : b;
                s2[e2] = y + dpp_mov<0x4E>(z);          // quad_perm xor2
            }
            float s3[2];
#pragma unroll
            for (int e2 = 0; e2 < 2; ++e2) {
                float a = s2[2 * e2], b = s2[2 * e2 + 1];
                float y = pb3 ? b : a, z = pb3 ? a : b;
                s3[e2] = y + dpp_mov<0x128>(z);         // row_ror:8 == xor8
            }
            {
                float a = s3[0], b = s3[1];
                float y = pb2 ? b : a, z = pb2 ? a : b;
                float fin = y + swz_xor4(z);            // ds_swizzle xor4 (symmetric)
                part[(size_t)(w01 * 128 + rl) * 16 + E] = fin;
            }
        }
    }
    __syncthreads();
    for (int idx = tid; idx < 2048; idx += 256) {
        float s = part[idx] + part[2048 + idx];
        atomicAdd(&logits[(size_t)(tile_m + (idx >> 4)) * NEXP + (idx & 15)], s);
    }
}

// softmax -> mask -> gates, k_per_token, and per-expert compacted token lists
__global__ void gates_kernel(const float* __restrict__ logits,
                             const float* __restrict__ b2,
                             float* __restrict__ gates, float* __restrict__ kout,
                             int* __restrict__ cnt, int* __restrict__ list) {
    const int t = blockIdx.x * 256 + threadIdx.x;
    float l[16];
    const float4* lp = (const float4*)(logits + (size_t)t * 16);
#pragma unroll
    for (int i = 0; i < 4; ++i) {
        float4 v = lp[i];
        l[i * 4] = v.x; l[i * 4 + 1] = v.y; l[i * 4 + 2] = v.z; l[i * 4 + 3] = v.w;
    }
#pragma unroll
    for (int i = 0; i < 16; ++i) l[i] += b2[i];
    float lmax = l[0];
#pragma unroll
    for (int i = 1; i < 16; ++i) lmax = fmaxf(lmax, l[i]);
    float p[16], S = 0.f;
#pragma unroll
    for (int i = 0; i < 16; ++i) { p[i] = expf(l[i] - lmax); S += p[i]; }
#pragma unroll
    for (int i = 0; i < 16; ++i) p[i] /= S;
    float pmax = p[0];
#pragma unroll
    for (int i = 1; i < 16; ++i) pmax = fmaxf(pmax, p[i]);
    const float thr = 0.5f * pmax;
    int k = 0;
    float g[16];
#pragma unroll
    for (int i = 0; i < 16; ++i) {
        bool m = p[i] >= thr;
        g[i] = m ? p[i] : 0.f;
        k += m ? 1 : 0;
        if (m) {
            int pos = atomicAdd(&cnt[i], 1);
            list[i * M_TOK + pos] = t;
        }
    }
    float4* gp = (float4*)(gates + (size_t)t * 16);
#pragma unroll
    for (int i = 0; i < 4; ++i)
        gp[i] = make_float4(g[i * 4], g[i * 4 + 1], g[i * 4 + 2], g[i * 4 + 3]);
    kout[t] = (float)k;
}

// out[t,:] = sum_e g[t,e] * be[e,:]  (base for the sparse atomic accumulate)
__global__ void init_out_kernel(const float* __restrict__ gates,
                                const float* __restrict__ be, float* __restrict__ out) {
    const int t = blockIdx.x;
    const int tid = threadIdx.x;
    __shared__ float g[16];
    if (tid < 16) g[tid] = gates[(size_t)t * 16 + tid];
    __syncthreads();
    const int c0 = tid * 8;
    float a[8] = {0.f, 0.f, 0.f, 0.f, 0.f, 0.f, 0.f, 0.f};
#pragma unroll
    for (int e = 0; e < 16; ++e) {
        float ge = g[e];
        if (ge != 0.f) {
            float4 v1 = *(const float4*)(be + (size_t)e * ODIM + c0);
            float4 v2 = *(const float4*)(be + (size_t)e * ODIM + c0 + 4);
            a[0] = fmaf(ge, v1.x, a[0]); a[1] = fmaf(ge, v1.y, a[1]);
            a[2] = fmaf(ge, v1.z, a[2]); a[3] = fmaf(ge, v1.w, a[3]);
            a[4] = fmaf(ge, v2.x, a[4]); a[5] = fmaf(ge, v2.y, a[5]);
            a[6] = fmaf(ge, v2.z, a[6]); a[7] = fmaf(ge, v2.w, a[7]);
        }
    }
    *(float4*)(out + (size_t)t * ODIM + c0)     = make_float4(a[0], a[1], a[2], a[3]);
    *(float4*)(out + (size_t)t * ODIM + c0 + 4) = make_float4(a[4], a[5], a[6], a[7]);
}

// Sparse expert GEMM: for expert e, gathered 128-token chunk, 128-col n-tile:
// out[tok,:] += g[tok,e] * (x[tok,:] @ We[e]).  K = 2048 (32 iters).
__global__ __launch_bounds__(256, 3) void moe_sparse_kernel(
    const ushort* __restrict__ xh, const ushort* __restrict__ weT,
    const float* __restrict__ gates, const int* __restrict__ cnt,
    const int* __restrict__ list, float* __restrict__ out) {
    const int bx = blockIdx.x;
    const int e = bx >> 10;
    const int chunk = (bx >> 4) & 63;
    const int ntile = bx & 15;
    const int ce = cnt[e];
    const int row0 = chunk << 7;
    if (row0 >= ce) return;
    const int rows = min(128, ce - row0);

    __shared__ ushort As[8192];
    __shared__ ushort Bs[8192];
    __shared__ int toks[128];
    __shared__ float gv[128];

    const int tid = threadIdx.x;
    if (tid < 128) {
        int t = list[e * M_TOK + row0 + min(tid, rows - 1)];
        toks[tid] = t;
        gv[tid] = gates[(size_t)t * NEXP + e];
    }
    __syncthreads();

    const int wave = tid >> 6, lane = tid & 63;
    const int q = lane >> 4, mrow = lane & 15;
    const int wm = (wave >> 1) << 6, wn = (wave & 1) << 6;

    // per-lane fixed staging pointers (A rows gathered; constant over K loop)
    const ushort* agp[4];
    const ushort* bgp[4];
    ushort* alp[4];
    ushort* blp[4];
    const ushort* wbase = weT + ((size_t)e * ODIM + (ntile << 7)) * DDIM;
#pragma unroll
    for (int j = 0; j < 4; ++j) {
        int L = wave * 256 + j * 64 + lane;
        int m = L >> 3;
        int kc = (L & 7) ^ (m & 7);
        agp[j] = xh + (size_t)toks[m] * DDIM + kc * 8;
        bgp[j] = wbase + (size_t)m * DDIM + kc * 8;
        alp[j] = As + (size_t)L * 8;
        blp[j] = Bs + (size_t)L * 8;
    }

    f32x4 acc[4][4];
#pragma unroll
    for (int i = 0; i < 4; ++i)
#pragma unroll
        for (int j = 0; j < 4; ++j) acc[i][j] = {0.f, 0.f, 0.f, 0.f};

    for (int it = 0; it < 32; ++it) {
        const int k0 = it << 6;
        __syncthreads();
#pragma unroll
        for (int j = 0; j < 4; ++j) {
            __builtin_amdgcn_global_load_lds(
                (const __attribute__((address_space(1))) void*)(agp[j] + k0),
                (__attribute__((address_space(3))) void*)alp[j], 16, 0, 0);
            __builtin_amdgcn_global_load_lds(
                (const __attribute__((address_space(1))) void*)(bgp[j] + k0),
                (__attribute__((address_space(3))) void*)blp[j], 16, 0, 0);
        }
        __syncthreads();
        mfma_step(As, Bs, wm, wn, mrow, q, acc);
    }

    // epilogue: atomic accumulate g * acc into out rows
#pragma unroll
    for (int i = 0; i < 4; ++i) {
        const int rl = wm + i * 16 + q * 4;
#pragma unroll
        for (int r = 0; r < 4; ++r) {
            const int lrow = rl + r;
            if (lrow < rows) {
                const int t = toks[lrow];
                const float g = gv[lrow];
                float* orow = out + (size_t)t * ODIM + (ntile << 7) + wn + mrow;
#pragma unroll
                for (int j = 0; j < 4; ++j)
                    atomicAdd(orow + j * 16, g * acc[i][j][r]);
            }
        }
    }
}

extern "C" void kernel_launch(void* const* d_in, const int* in_sizes, int n_in,
                              void* d_out, int out_size, void* d_ws, size_t ws_size,
                              hipStream_t stream) {
    const float* x  = (const float*)d_in[0];
    const float* W1 = (const float*)d_in[1];
    const float* b1 = (const float*)d_in[2];
    const float* W2 = (const float*)d_in[3];
    const float* b2 = (const float*)d_in[4];
    const float* We = (const float*)d_in[5];
    const float* be = (const float*)d_in[6];
    float* out  = (float*)d_out;
    float* kout = out + (size_t)M_TOK * ODIM;

    char* ws = (char*)d_ws;
    ushort* x_hi   = (ushort*)(ws);                 //  33,554,432 B
    ushort* x_lo   = (ushort*)(ws + 33554432);      //  33,554,432 B
    ushort* w1t_hi = (ushort*)(ws + 67108864);      //  16,777,216 B
    // w1t_lo region is dead after gemm1; cnt/list reuse it:
    ushort* w1t_lo = (ushort*)(ws + 83886080);      //  16,777,216 B
    int*    cnt    = (int*)   (ws + 83886080);      //  64 B (after gemm1)
    int*    list   = (int*)   (ws + 83887104);      //  512 KiB (after gemm1)
    ushort* weT    = (ushort*)(ws + 100663296);     // 134,217,728 B
    float*  logits = (float*) (ws + 234881024);     //  512 KiB
    float*  gates  = (float*) (ws + 235405312);     //  512 KiB

    hipMemsetAsync(logits, 0, (size_t)M_TOK * NEXP * sizeof(float), stream);
    split_x_kernel<<<16384, 256, 0, stream>>>(x, x_hi, x_lo);
    transpose_split_w1_kernel<<<2048, 256, 0, stream>>>(W1, w1t_hi, w1t_lo);
    gemm1_kernel<<<2048, 256, 0, stream>>>(x_hi, x_lo, w1t_hi, w1t_lo, b1, W2, logits);
    hipMemsetAsync(cnt, 0, 64, stream);
    gates_kernel<<<32, 256, 0, stream>>>(logits, b2, gates, kout, cnt, list);
    dim3 gwe(1024, 16);
    transpose_we_kernel<<<gwe, 256, 0, stream>>>(We, weT);
    init_out_kernel<<<M_TOK, 256, 0, stream>>>(gates, be, out);
    moe_sparse_kernel<<<16384, 256, 0, stream>>>(x_hi, weT, gates, cnt, list, out);
}

// Round 5
// 1198.048 us; speedup vs baseline: 1.0248x; 1.0223x over previous
//
#include <hip/hip_runtime.h>
#include <stdint.h>

#define M_TOK 8192   // B*T
#define DDIM  2048
#define HDIM  4096
#define NEXP  16
#define ODIM  2048

typedef __attribute__((ext_vector_type(8))) __bf16 bf16x8;
typedef __attribute__((ext_vector_type(4))) float  f32x4;

__device__ __forceinline__ unsigned short f2bf(float f) {
    unsigned int u = __float_as_uint(f);
    unsigned int r = (u + 0x7FFFu + ((u >> 16) & 1u)) >> 16;   // RNE
    return (unsigned short)r;
}
__device__ __forceinline__ float bf2f(unsigned short s) {
    return __uint_as_float(((unsigned int)s) << 16);
}

// DPP move (returns the lane-permuted copy; full row/bank masks, bound_ctrl on).
// Only direction-unambiguous controls: quad_perm (explicit map) and row_ror:8
// (== xor8 under either rotation convention).
template <int CTRL>
__device__ __forceinline__ float dpp_mov(float x) {
    return __int_as_float(
        __builtin_amdgcn_update_dpp(0, __float_as_int(x), CTRL, 0xF, 0xF, true));
}
// xor4 lane exchange via ds_swizzle BitMode (symmetric — verified r3/r4):
__device__ __forceinline__ float swz_xor4(float x) {
    return __int_as_float(__builtin_amdgcn_ds_swizzle(__float_as_int(x), 0x101F));
}

// ---------------- preprocessing ----------------

__global__ void split_x_kernel(const float* __restrict__ x,
                               ushort* __restrict__ xh, ushort* __restrict__ xl) {
    size_t i = ((size_t)blockIdx.x * 256 + threadIdx.x) * 4;
    float4 v = *(const float4*)(x + i);
    float f[4] = {v.x, v.y, v.z, v.w};
    ushort hu[4], lu[4];
#pragma unroll
    for (int u = 0; u < 4; ++u) {
        hu[u] = f2bf(f[u]);
        lu[u] = f2bf(f[u] - bf2f(hu[u]));
    }
    *(ushort4*)(xh + i) = make_ushort4(hu[0], hu[1], hu[2], hu[3]);
    *(ushort4*)(xl + i) = make_ushort4(lu[0], lu[1], lu[2], lu[3]);
}

__global__ void transpose_split_w1_kernel(const float* __restrict__ W1,
                                          ushort* __restrict__ th, ushort* __restrict__ tl) {
    __shared__ float tile[64][65];
    int h0 = (blockIdx.x & 63) * 64;
    int d0 = (blockIdx.x >> 6) * 64;
    int r = threadIdx.x >> 4;
    int c = (threadIdx.x & 15) * 4;
#pragma unroll
    for (int rr = 0; rr < 4; ++rr) {
        int row = rr * 16 + r;
        float4 v = *(const float4*)(W1 + (size_t)(d0 + row) * HDIM + h0 + c);
        tile[row][c + 0] = v.x; tile[row][c + 1] = v.y;
        tile[row][c + 2] = v.z; tile[row][c + 3] = v.w;
    }
    __syncthreads();
#pragma unroll
    for (int rr = 0; rr < 4; ++rr) {
        int hrow = rr * 16 + r;
        ushort hu[4], lu[4];
#pragma unroll
        for (int u = 0; u < 4; ++u) {
            float f = tile[c + u][hrow];
            hu[u] = f2bf(f);
            lu[u] = f2bf(f - bf2f(hu[u]));
        }
        size_t o = (size_t)(h0 + hrow) * DDIM + d0 + c;
        *(ushort4*)(th + o) = make_ushort4(hu[0], hu[1], hu[2], hu[3]);
        *(ushort4*)(tl + o) = make_ushort4(lu[0], lu[1], lu[2], lu[3]);
    }
}

__global__ void transpose_we_kernel(const float* __restrict__ We, ushort* __restrict__ wt) {
    __shared__ float tile[64][65];
    int e = blockIdx.y;
    int o0 = (blockIdx.x & 31) * 64;
    int d0 = (blockIdx.x >> 5) * 64;
    const float* src = We + (size_t)e * DDIM * ODIM;
    ushort* dst = wt + (size_t)e * ODIM * DDIM;
    int r = threadIdx.x >> 4;
    int c = (threadIdx.x & 15) * 4;
#pragma unroll
    for (int rr = 0; rr < 4; ++rr) {
        int row = rr * 16 + r;
        float4 v = *(const float4*)(src + (size_t)(d0 + row) * ODIM + o0 + c);
        tile[row][c + 0] = v.x; tile[row][c + 1] = v.y;
        tile[row][c + 2] = v.z; tile[row][c + 3] = v.w;
    }
    __syncthreads();
#pragma unroll
    for (int rr = 0; rr < 4; ++rr) {
        int orow = rr * 16 + r;
        ushort hu[4];
#pragma unroll
        for (int u = 0; u < 4; ++u) hu[u] = f2bf(tile[c + u][orow]);
        *(ushort4*)(dst + (size_t)(o0 + orow) * DDIM + d0 + c) =
            make_ushort4(hu[0], hu[1], hu[2], hu[3]);
    }
}

// ---------------- GEMM core helpers (xor-swizzled LDS, 16B global_load_lds) ----------

__device__ __forceinline__ void stage_tile(const ushort* __restrict__ g0, int ld,
                                           ushort* lds0, int wave, int lane) {
#pragma unroll
    for (int j = 0; j < 4; ++j) {
        int L = wave * 256 + j * 64 + lane;
        int m = L >> 3;
        int kc = (L & 7) ^ (m & 7);
        const ushort* gp = g0 + (size_t)m * ld + kc * 8;
        ushort* lp = lds0 + (size_t)(wave * 256 + j * 64) * 8;
        __builtin_amdgcn_global_load_lds(
            (const __attribute__((address_space(1))) void*)gp,
            (__attribute__((address_space(3))) void*)lp, 16, 0, 0);
    }
}

__device__ __forceinline__ bf16x8 ldfrag(const ushort* lds0, int row, int kc) {
    return *(const bf16x8*)(lds0 + ((row << 3) + (kc ^ (row & 7))) * 8);
}

__device__ __forceinline__ void mfma_step(const ushort* As, const ushort* Bs,
                                          int wm, int wn, int mrow, int q,
                                          f32x4 (&acc)[4][4]) {
#pragma unroll
    for (int s = 0; s < 2; ++s) {
        bf16x8 af[4], bfr[4];
#pragma unroll
        for (int i = 0; i < 4; ++i) af[i] = ldfrag(As, wm + i * 16 + mrow, s * 4 + q);
#pragma unroll
        for (int j = 0; j < 4; ++j) bfr[j] = ldfrag(Bs, wn + j * 16 + mrow, s * 4 + q);
#pragma unroll
        for (int i = 0; i < 4; ++i)
#pragma unroll
            for (int j = 0; j < 4; ++j)
                acc[i][j] = __builtin_amdgcn_mfma_f32_16x16x32_bf16(
                    af[i], bfr[j], acc[i][j], 0, 0, 0);
    }
}

// Router GEMM1 + fused GEMM2, 256x256 tile, 8 waves, double-buffered LDS with
// COUNTED vmcnt (never 0 in steady state) — T3/T4 structure:
//   per K-tile: frag-read -> lgkm drain -> barrier -> stage(kt+2) -> 64 MFMA
//               -> vmcnt(8) -> barrier
// The 2-barrier 128^2 structure plateaued at ~1033 TF (r0-r4); __syncthreads
// dbuf fails (r3: vmcnt(0) drain + LDS occupancy cliff).
__global__ __launch_bounds__(512, 2) void gemm1_kernel(
    const ushort* __restrict__ xh, const ushort* __restrict__ xl,
    const ushort* __restrict__ wh, const ushort* __restrict__ wl,
    const float* __restrict__ b1, const float* __restrict__ W2,
    float* __restrict__ logits) {
    __shared__ ushort lds[65536];            // 128 KiB: A0|B0|A1|B1 (32 KiB each)
    ushort* const A0 = lds;
    ushort* const B0 = lds + 16384;
    ushort* const A1 = lds + 32768;
    ushort* const B1 = lds + 49152;

    const int tile_m = (blockIdx.x >> 4) << 8;   // 32 m-tiles of 256
    const int tile_n = (blockIdx.x & 15) << 8;   // 16 n-tiles of 256
    const int tid = threadIdx.x;
    const int wave = tid >> 6, lane = tid & 63;
    const int q = lane >> 4, mrow = lane & 15;
    const int wr = (wave >> 2) << 7;             // wave row base: 0 / 128
    const int wcb = (wave & 3) << 6;             // wave col base: 0/64/128/192

    // per-lane staging offsets (A and B share the same pattern and ld=DDIM)
    unsigned goff[4];
    int ldso[4];
#pragma unroll
    for (int j = 0; j < 4; ++j) {
        int L = wave * 256 + j * 64 + lane;      // 0..2047
        int m = L >> 3;                          // 0..255
        int kc = (L & 7) ^ (m & 7);
        goff[j] = (unsigned)m * DDIM + kc * 8;
        ldso[j] = L * 8;
    }

    f32x4 acc[8][4];
#pragma unroll
    for (int i = 0; i < 8; ++i)
#pragma unroll
        for (int j = 0; j < 4; ++j) acc[i][j] = {0.f, 0.f, 0.f, 0.f};

#define SRC_A(t) ((((t) >> 5) == 1 ? xl : xh) + (size_t)tile_m * DDIM + (((t) & 31) << 6))
#define SRC_B(t) ((((t) >> 5) == 2 ? wl : wh) + (size_t)tile_n * DDIM + (((t) & 31) << 6))
#define STAGE(srcp, dstp)                                                           \
    {                                                                               \
        const ushort* _s = (srcp);                                                  \
        ushort* _d = (dstp);                                                        \
        _Pragma("unroll")                                                           \
        for (int _j = 0; _j < 4; ++_j)                                              \
            __builtin_amdgcn_global_load_lds(                                       \
                (const __attribute__((address_space(1))) void*)(_s + goff[_j]),     \
                (__attribute__((address_space(3))) void*)(_d + ldso[_j]), 16, 0, 0);\
    }

    // prologue: tiles 0 and 1 in flight (16 loads); wait for tile 0's 8
    STAGE(SRC_A(0), A0); STAGE(SRC_B(0), B0);
    STAGE(SRC_A(1), A1); STAGE(SRC_B(1), B1);
    asm volatile("s_waitcnt vmcnt(8)" ::: "memory");
    __builtin_amdgcn_s_barrier();
    __builtin_amdgcn_sched_barrier(0);

    for (int kt = 0; kt < 96; ++kt) {
        ushort* As = (kt & 1) ? A1 : A0;
        ushort* Bs = (kt & 1) ? B1 : B0;
        bf16x8 a0[8], a1[8], bv0[4], bv1[4];
#pragma unroll
        for (int i = 0; i < 8; ++i) {
            a0[i] = ldfrag(As, wr + i * 16 + mrow, q);
            a1[i] = ldfrag(As, wr + i * 16 + mrow, 4 + q);
        }
#pragma unroll
        for (int j = 0; j < 4; ++j) {
            bv0[j] = ldfrag(Bs, wcb + j * 16 + mrow, q);
            bv1[j] = ldfrag(Bs, wcb + j * 16 + mrow, 4 + q);
        }
        // all of this wave's reads of As/Bs complete BEFORE the barrier
        asm volatile("s_waitcnt lgkmcnt(0)" ::: "memory");
        __builtin_amdgcn_sched_barrier(0);
        __builtin_amdgcn_s_barrier();
        __builtin_amdgcn_sched_barrier(0);
        // now every wave is done reading this buffer: overwrite it (async)
        if (kt + 2 < 96) {
            STAGE(SRC_A(kt + 2), As);
            STAGE(SRC_B(kt + 2), Bs);
        }
#pragma unroll
        for (int i = 0; i < 8; ++i)
#pragma unroll
            for (int j = 0; j < 4; ++j)
                acc[i][j] = __builtin_amdgcn_mfma_f32_16x16x32_bf16(
                    a0[i], bv0[j], acc[i][j], 0, 0, 0);
#pragma unroll
        for (int i = 0; i < 8; ++i)
#pragma unroll
            for (int j = 0; j < 4; ++j)
                acc[i][j] = __builtin_amdgcn_mfma_f32_16x16x32_bf16(
                    a1[i], bv1[j], acc[i][j], 0, 0, 0);
        // gate the NEXT tile: 16 outstanding -> wait to 8 (tile kt+1 done);
        // tail (no stage issued): drain fully
        if (kt + 2 < 96) {
            asm volatile("s_waitcnt vmcnt(8)" ::: "memory");
        } else {
            asm volatile("s_waitcnt vmcnt(0)" ::: "memory");
        }
        __builtin_amdgcn_s_barrier();
        __builtin_amdgcn_sched_barrier(0);
    }
#undef SRC_A
#undef SRC_B
#undef STAGE

    // ---- fused epilogue: partial logits from this 256x256 h-tile ----
    float b1v[4];
    f32x4 w2r[4][4];
#pragma unroll
    for (int j = 0; j < 4; ++j) {
        const int cc = tile_n + wcb + j * 16 + mrow;
        b1v[j] = b1[cc];
        const float4* wp = (const float4*)(W2 + (size_t)cc * NEXP);
#pragma unroll
        for (int qq = 0; qq < 4; ++qq) {
            float4 v = wp[qq];
            w2r[j][qq] = (f32x4){v.x, v.y, v.z, v.w};
        }
    }
    __syncthreads();
    float* part = (float*)lds;       // [4 wc][256 rows][16 E] = 64 KiB
    const int pw = wave & 3;
    const bool pb0 = (mrow & 1) != 0, pb1 = (mrow & 2) != 0;
    const bool pb2 = (mrow & 4) != 0, pb3 = (mrow & 8) != 0;
    const int E = (mrow & 3) | ((mrow & 8) >> 1) | ((mrow & 4) << 1);
#pragma unroll
    for (int i = 0; i < 8; ++i) {
#pragma unroll
        for (int r = 0; r < 4; ++r) {
            const int rl = wr + i * 16 + q * 4 + r;
            float ll[16];
#pragma unroll
            for (int e = 0; e < 16; ++e) ll[e] = 0.f;
#pragma unroll
            for (int j = 0; j < 4; ++j) {
                float v = acc[i][j][r] + b1v[j];
                v = v > 0.f ? v : 0.f;
#pragma unroll
                for (int e = 0; e < 16; ++e)
                    ll[e] = fmaf(v, w2r[j][e >> 2][e & 3], ll[e]);
            }
            // halving tree across 16 mrow lanes: 16 -> 8 -> 4 -> 2 -> 1
            float s1[8];
#pragma unroll
            for (int e2 = 0; e2 < 8; ++e2) {
                float a = ll[2 * e2], b = ll[2 * e2 + 1];
                float y = pb0 ? b : a, z = pb0 ? a : b;
                s1[e2] = y + dpp_mov<0xB1>(z);          // quad_perm xor1
            }
            float s2[4];
#pragma unroll
            for (int e2 = 0; e2 < 4; ++e2) {
                float a = s1[2 * e2], b = s1[2 * e2 + 1];
                float y = pb1 ? b : a, z = pb1 ? a : b;
                s2[e2] = y + dpp_mov<0x4E>(z);          // quad_perm xor2
            }
            float s3[2];
#pragma unroll
            for (int e2 = 0; e2 < 2; ++e2) {
                float a = s2[2 * e2], b = s2[2 * e2 + 1];
                float y = pb3 ? b : a, z = pb3 ? a : b;
                s3[e2] = y + dpp_mov<0x128>(z);         // row_ror:8 == xor8
            }
            {
                float a = s3[0], b = s3[1];
                float y = pb2 ? b : a, z = pb2 ? a : b;
                float fin = y + swz_xor4(z);            // ds_swizzle xor4
                part[((size_t)(pw << 8) + rl) * 16 + E] = fin;
            }
        }
    }
    __syncthreads();
    for (int idx = tid; idx < 4096; idx += 512) {
        float s = part[idx] + part[4096 + idx] + part[8192 + idx] + part[12288 + idx];
        atomicAdd(&logits[(size_t)(tile_m + (idx >> 4)) * NEXP + (idx & 15)], s);
    }
}

// softmax -> mask -> gates, k_per_token, and per-expert compacted token lists
__global__ void gates_kernel(const float* __restrict__ logits,
                             const float* __restrict__ b2,
                             float* __restrict__ gates, float* __restrict__ kout,
                             int* __restrict__ cnt, int* __restrict__ list) {
    const int t = blockIdx.x * 256 + threadIdx.x;
    float l[16];
    const float4* lp = (const float4*)(logits + (size_t)t * 16);
#pragma unroll
    for (int i = 0; i < 4; ++i) {
        float4 v = lp[i];
        l[i * 4] = v.x; l[i * 4 + 1] = v.y; l[i * 4 + 2] = v.z; l[i * 4 + 3] = v.w;
    }
#pragma unroll
    for (int i = 0; i < 16; ++i) l[i] += b2[i];
    float lmax = l[0];
#pragma unroll
    for (int i = 1; i < 16; ++i) lmax = fmaxf(lmax, l[i]);
    float p[16], S = 0.f;
#pragma unroll
    for (int i = 0; i < 16; ++i) { p[i] = expf(l[i] - lmax); S += p[i]; }
#pragma unroll
    for (int i = 0; i < 16; ++i) p[i] /= S;
    float pmax = p[0];
#pragma unroll
    for (int i = 1; i < 16; ++i) pmax = fmaxf(pmax, p[i]);
    const float thr = 0.5f * pmax;
    int k = 0;
    float g[16];
#pragma unroll
    for (int i = 0; i < 16; ++i) {
        bool m = p[i] >= thr;
        g[i] = m ? p[i] : 0.f;
        k += m ? 1 : 0;
        if (m) {
            int pos = atomicAdd(&cnt[i], 1);
            list[i * M_TOK + pos] = t;
        }
    }
    float4* gp = (float4*)(gates + (size_t)t * 16);
#pragma unroll
    for (int i = 0; i < 4; ++i)
        gp[i] = make_float4(g[i * 4], g[i * 4 + 1], g[i * 4 + 2], g[i * 4 + 3]);
    kout[t] = (float)k;
}

// out[t,:] = sum_e g[t,e] * be[e,:]  (base for the sparse atomic accumulate)
__global__ void init_out_kernel(const float* __restrict__ gates,
                                const float* __restrict__ be, float* __restrict__ out) {
    const int t = blockIdx.x;
    const int tid = threadIdx.x;
    __shared__ float g[16];
    if (tid < 16) g[tid] = gates[(size_t)t * 16 + tid];
    __syncthreads();
    const int c0 = tid * 8;
    float a[8] = {0.f, 0.f, 0.f, 0.f, 0.f, 0.f, 0.f, 0.f};
#pragma unroll
    for (int e = 0; e < 16; ++e) {
        float ge = g[e];
        if (ge != 0.f) {
            float4 v1 = *(const float4*)(be + (size_t)e * ODIM + c0);
            float4 v2 = *(const float4*)(be + (size_t)e * ODIM + c0 + 4);
            a[0] = fmaf(ge, v1.x, a[0]); a[1] = fmaf(ge, v1.y, a[1]);
            a[2] = fmaf(ge, v1.z, a[2]); a[3] = fmaf(ge, v1.w, a[3]);
            a[4] = fmaf(ge, v2.x, a[4]); a[5] = fmaf(ge, v2.y, a[5]);
            a[6] = fmaf(ge, v2.z, a[6]); a[7] = fmaf(ge, v2.w, a[7]);
        }
    }
    *(float4*)(out + (size_t)t * ODIM + c0)     = make_float4(a[0], a[1], a[2], a[3]);
    *(float4*)(out + (size_t)t * ODIM + c0 + 4) = make_float4(a[4], a[5], a[6], a[7]);
}

// Sparse expert GEMM: for expert e, gathered 128-token chunk, 128-col n-tile:
// out[tok,:] += g[tok,e] * (x[tok,:] @ We[e]).  K = 2048 (32 iters).
__global__ __launch_bounds__(256, 3) void moe_sparse_kernel(
    const ushort* __restrict__ xh, const ushort* __restrict__ weT,
    const float* __restrict__ gates, const int* __restrict__ cnt,
    const int* __restrict__ list, float* __restrict__ out) {
    const int bx = blockIdx.x;
    const int e = bx >> 10;
    const int chunk = (bx >> 4) & 63;
    const int ntile = bx & 15;
    const int ce = cnt[e];
    const int row0 = chunk << 7;
    if (row0 >= ce) return;
    const int rows = min(128, ce - row0);

    __shared__ ushort As[8192];
    __shared__ ushort Bs[8192];
    __shared__ int toks[128];
    __shared__ float gv[128];

    const int tid = threadIdx.x;
    if (tid < 128) {
        int t = list[e * M_TOK + row0 + min(tid, rows - 1)];
        toks[tid] = t;
        gv[tid] = gates[(size_t)t * NEXP + e];
    }
    __syncthreads();

    const int wave = tid >> 6, lane = tid & 63;
    const int q = lane >> 4, mrow = lane & 15;
    const int wm = (wave >> 1) << 6, wn = (wave & 1) << 6;

    // per-lane fixed staging pointers (A rows gathered; constant over K loop)
    const ushort* agp[4];
    const ushort* bgp[4];
    ushort* alp[4];
    ushort* blp[4];
    const ushort* wbase = weT + ((size_t)e * ODIM + (ntile << 7)) * DDIM;
#pragma unroll
    for (int j = 0; j < 4; ++j) {
        int L = wave * 256 + j * 64 + lane;
        int m = L >> 3;
        int kc = (L & 7) ^ (m & 7);
        agp[j] = xh + (size_t)toks[m] * DDIM + kc * 8;
        bgp[j] = wbase + (size_t)m * DDIM + kc * 8;
        alp[j] = As + (size_t)L * 8;
        blp[j] = Bs + (size_t)L * 8;
    }

    f32x4 acc[4][4];
#pragma unroll
    for (int i = 0; i < 4; ++i)
#pragma unroll
        for (int j = 0; j < 4; ++j) acc[i][j] = {0.f, 0.f, 0.f, 0.f};

    for (int it = 0; it < 32; ++it) {
        const int k0 = it << 6;
        __syncthreads();
#pragma unroll
        for (int j = 0; j < 4; ++j) {
            __builtin_amdgcn_global_load_lds(
                (const __attribute__((address_space(1))) void*)(agp[j] + k0),
                (__attribute__((address_space(3))) void*)alp[j], 16, 0, 0);
            __builtin_amdgcn_global_load_lds(
                (const __attribute__((address_space(1))) void*)(bgp[j] + k0),
                (__attribute__((address_space(3))) void*)blp[j], 16, 0, 0);
        }
        __syncthreads();
        mfma_step(As, Bs, wm, wn, mrow, q, acc);
    }

    // epilogue: atomic accumulate g * acc into out rows
#pragma unroll
    for (int i = 0; i < 4; ++i) {
        const int rl = wm + i * 16 + q * 4;
#pragma unroll
        for (int r = 0; r < 4; ++r) {
            const int lrow = rl + r;
            if (lrow < rows) {
                const int t = toks[lrow];
                const float g = gv[lrow];
                float* orow = out + (size_t)t * ODIM + (ntile << 7) + wn + mrow;
#pragma unroll
                for (int j = 0; j < 4; ++j)
                    atomicAdd(orow + j * 16, g * acc[i][j][r]);
            }
        }
    }
}

extern "C" void kernel_launch(void* const* d_in, const int* in_sizes, int n_in,
                              void* d_out, int out_size, void* d_ws, size_t ws_size,
                              hipStream_t stream) {
    const float* x  = (const float*)d_in[0];
    const float* W1 = (const float*)d_in[1];
    const float* b1 = (const float*)d_in[2];
    const float* W2 = (const float*)d_in[3];
    const float* b2 = (const float*)d_in[4];
    const float* We = (const float*)d_in[5];
    const float* be = (const float*)d_in[6];
    float* out  = (float*)d_out;
    float* kout = out + (size_t)M_TOK * ODIM;

    char* ws = (char*)d_ws;
    ushort* x_hi   = (ushort*)(ws);                 //  33,554,432 B
    ushort* x_lo   = (ushort*)(ws + 33554432);      //  33,554,432 B
    ushort* w1t_hi = (ushort*)(ws + 67108864);      //  16,777,216 B
    // w1t_lo region is dead after gemm1; cnt/list reuse it:
    ushort* w1t_lo = (ushort*)(ws + 83886080);      //  16,777,216 B
    int*    cnt    = (int*)   (ws + 83886080);      //  64 B (after gemm1)
    int*    list   = (int*)   (ws + 83887104);      //  512 KiB (after gemm1)
    ushort* weT    = (ushort*)(ws + 100663296);     // 134,217,728 B
    float*  logits = (float*) (ws + 234881024);     //  512 KiB
    float*  gates  = (float*) (ws + 235405312);     //  512 KiB

    hipMemsetAsync(logits, 0, (size_t)M_TOK * NEXP * sizeof(float), stream);
    split_x_kernel<<<16384, 256, 0, stream>>>(x, x_hi, x_lo);
    transpose_split_w1_kernel<<<2048, 256, 0, stream>>>(W1, w1t_hi, w1t_lo);
    gemm1_kernel<<<512, 512, 0, stream>>>(x_hi, x_lo, w1t_hi, w1t_lo, b1, W2, logits);
    hipMemsetAsync(cnt, 0, 64, stream);
    gates_kernel<<<32, 256, 0, stream>>>(logits, b2, gates, kout, cnt, list);
    dim3 gwe(1024, 16);
    transpose_we_kernel<<<gwe, 256, 0, stream>>>(We, weT);
    init_out_kernel<<<M_TOK, 256, 0, stream>>>(gates, be, out);
    moe_sparse_kernel<<<16384, 256, 0, stream>>>(x_hi, weT, gates, cnt, list, out);
}